// Round 4
// baseline (4855.760 us; speedup 1.0000x reference)
//
#include <hip/hip_runtime.h>
#include <math.h>

// SentenceDecoder: B=64, D=512, H=1024, V=32000, L=2, T=32. NG = 4H = 4096.
// All GEMMs run as split-bf16 MFMA (x = hi + lo bf16, 3 MFMA per product term
// group: hi*lo + lo*hi + hi*hi, fp32 accumulate; rel err ~2^-17 — argmax-safe).
// Fragment-native layout: [(row*KG + kg)*16 + {0..7 hi, 8..15 lo}], kg = k/8.
#define BB 64
#define DD 512
#define HH 1024
#define VV 32000
#define NG 4096
#define TT 32
#define NSPLIT 8            // K-slices for gate GEMMs (partials summed in cell_k)
#define LBLK 1000           // V / 32 logits tiles
#define KGC0 192            // kg per row, layer-0 concat K=1536 (x512|h1024)
#define KGC1 256            // layer-1 concat K=2048 (h0|h1)
#define KGL  128            // logits K=1024

typedef __bf16 bf16x8 __attribute__((ext_vector_type(8)));
typedef float  f32x4  __attribute__((ext_vector_type(4)));

// split fp32 into bf16 hi + bf16 lo (RN-even both): x ~= hi + lo
__device__ __forceinline__ void split_bf16(float x, unsigned short* hi, unsigned short* lo)
{
    unsigned u = __float_as_uint(x);
    unsigned r = (u + 0x7fffu + ((u >> 16) & 1u)) & 0xffff0000u;
    *hi = (unsigned short)(r >> 16);
    float rem = x - __uint_as_float(r);
    unsigned u2 = __float_as_uint(rem);
    unsigned r2 = u2 + 0x7fffu + ((u2 >> 16) & 1u);
    *lo = (unsigned short)(r2 >> 16);
}

__device__ __forceinline__ unsigned pack2(unsigned short a, unsigned short b)
{
    return (unsigned)a | ((unsigned)b << 16);
}

// ---------------------------------------------------------------------------
// split_mat_k: fp32 [R][Ksrc] row-major -> split fragment layout at kg offset.
// One thread per (row, kg): t>>kshift = row, t&mask = kg, Ksrc = 8<<kshift.
// ---------------------------------------------------------------------------
__global__ __launch_bounds__(256)
void split_mat_k(const float* __restrict__ src, unsigned short* __restrict__ dst,
                 int kshift, int KGdst, int kgoff)
{
    const size_t t = (size_t)blockIdx.x * 256 + threadIdx.x;
    const int row = (int)(t >> kshift);
    const int kg  = (int)(t & ((1u << kshift) - 1));
    const float* wp = src + (t << 3);
    const float4 w0 = *(const float4*)wp;
    const float4 w1 = *(const float4*)(wp + 4);
    const float v[8] = {w0.x, w0.y, w0.z, w0.w, w1.x, w1.y, w1.z, w1.w};
    unsigned short hs[8], ls[8];
#pragma unroll
    for (int i = 0; i < 8; i++) split_bf16(v[i], &hs[i], &ls[i]);
    uint4 uh, ul;
    uh.x = pack2(hs[0], hs[1]); uh.y = pack2(hs[2], hs[3]);
    uh.z = pack2(hs[4], hs[5]); uh.w = pack2(hs[6], hs[7]);
    ul.x = pack2(ls[0], ls[1]); ul.y = pack2(ls[2], ls[3]);
    ul.z = pack2(ls[4], ls[5]); ul.w = pack2(ls[6], ls[7]);
    unsigned short* o = dst + (((size_t)row * KGdst + kgoff + kg) << 4);
    *(uint4*)o       = uh;
    *(uint4*)(o + 8) = ul;
}

// ---------------------------------------------------------------------------
// kloop: software-pipelined split-bf16 MFMA K-loop. Wave computes a 16x32
// C-tile (rows = its 16 batch rows, cols = n0..n0+31 via two 16-wide accs).
// Window w covers k = 32w..32w+31; quad q holds kg = 4w+q (folded into the
// base pointers). Next window's 6 fragment loads are issued BEFORE current
// window's 6 MFMAs -> ~12 loads in flight per wave (vmcnt(6) steady state).
// ---------------------------------------------------------------------------
__device__ __forceinline__ void kloop(const unsigned short* __restrict__ pa,
                                      const unsigned short* __restrict__ pw0,
                                      const unsigned short* __restrict__ pw1,
                                      int count, f32x4& a0, f32x4& a1)
{
    bf16x8 cah  = *(const bf16x8*)(pa);
    bf16x8 cal  = *(const bf16x8*)(pa + 8);
    bf16x8 cb0h = *(const bf16x8*)(pw0);
    bf16x8 cb0l = *(const bf16x8*)(pw0 + 8);
    bf16x8 cb1h = *(const bf16x8*)(pw1);
    bf16x8 cb1l = *(const bf16x8*)(pw1 + 8);

#pragma unroll 2
    for (int w = 1; w < count; ++w) {
        const int off = w << 6;            // 4 kg * 16 ushorts per window
        bf16x8 nah  = *(const bf16x8*)(pa + off);
        bf16x8 nal  = *(const bf16x8*)(pa + off + 8);
        bf16x8 nb0h = *(const bf16x8*)(pw0 + off);
        bf16x8 nb0l = *(const bf16x8*)(pw0 + off + 8);
        bf16x8 nb1h = *(const bf16x8*)(pw1 + off);
        bf16x8 nb1l = *(const bf16x8*)(pw1 + off + 8);

        a0 = __builtin_amdgcn_mfma_f32_16x16x32_bf16(cah, cb0l, a0, 0, 0, 0);
        a0 = __builtin_amdgcn_mfma_f32_16x16x32_bf16(cal, cb0h, a0, 0, 0, 0);
        a0 = __builtin_amdgcn_mfma_f32_16x16x32_bf16(cah, cb0h, a0, 0, 0, 0);
        a1 = __builtin_amdgcn_mfma_f32_16x16x32_bf16(cah, cb1l, a1, 0, 0, 0);
        a1 = __builtin_amdgcn_mfma_f32_16x16x32_bf16(cal, cb1h, a1, 0, 0, 0);
        a1 = __builtin_amdgcn_mfma_f32_16x16x32_bf16(cah, cb1h, a1, 0, 0, 0);

        cah = nah; cal = nal; cb0h = nb0h; cb0l = nb0l; cb1h = nb1h; cb1l = nb1l;
    }
    a0 = __builtin_amdgcn_mfma_f32_16x16x32_bf16(cah, cb0l, a0, 0, 0, 0);
    a0 = __builtin_amdgcn_mfma_f32_16x16x32_bf16(cal, cb0h, a0, 0, 0, 0);
    a0 = __builtin_amdgcn_mfma_f32_16x16x32_bf16(cah, cb0h, a0, 0, 0, 0);
    a1 = __builtin_amdgcn_mfma_f32_16x16x32_bf16(cah, cb1l, a1, 0, 0, 0);
    a1 = __builtin_amdgcn_mfma_f32_16x16x32_bf16(cal, cb1h, a1, 0, 0, 0);
    a1 = __builtin_amdgcn_mfma_f32_16x16x32_bf16(cah, cb1h, a1, 0, 0, 0);
}

// ---------------------------------------------------------------------------
// gates_mfma_k: partial gate GEMM, 64x32 tile, K-slice = blockIdx.y.
// P[slice][b][j] = sum_{k in slice} A[b][k] * W[j][k]. Grid (128, NSPLIT).
// ---------------------------------------------------------------------------
__global__ __launch_bounds__(256)
void gates_mfma_k(const unsigned short* __restrict__ A2,
                  const unsigned short* __restrict__ W2,
                  int KGk, int count, float* __restrict__ P)
{
    const int n0  = blockIdx.x * 32;
    const int tid = threadIdx.x;
    const int wv = tid >> 6, lane = tid & 63, l15 = lane & 15, q = lane >> 4;
    const int kg0 = blockIdx.y * count * 4 + q;

    const unsigned short* pa  = A2 + (((size_t)(16 * wv + l15) * KGk + kg0) << 4);
    const unsigned short* pw0 = W2 + (((size_t)(n0 + l15)      * KGk + kg0) << 4);
    const unsigned short* pw1 = W2 + (((size_t)(n0 + 16 + l15) * KGk + kg0) << 4);

    f32x4 a0 = {0, 0, 0, 0}, a1 = {0, 0, 0, 0};
    kloop(pa, pw0, pw1, count, a0, a1);

    float* __restrict__ Pout = P + (size_t)blockIdx.y * (BB * NG);
    // C/D: col = lane&15 (n), row = q*4 + reg (m)  [r2/r3-verified]
#pragma unroll
    for (int reg = 0; reg < 4; reg++) {
        const int b = 16 * wv + q * 4 + reg;
        Pout[(size_t)b * NG + n0 + l15]      = a0[reg];
        Pout[(size_t)b * NG + n0 + 16 + l15] = a1[reg];
    }
}

// ---------------------------------------------------------------------------
// cell_k: sum NSPLIT partial slices + biases -> gates; LSTM cell; emit split
// h into two fragment-layout destinations (next consumer GEMMs).
// ---------------------------------------------------------------------------
__global__ __launch_bounds__(256)
void cell_k(const float* __restrict__ P, const float* __restrict__ bih,
            const float* __restrict__ bhh, float* __restrict__ c,
            unsigned short* __restrict__ dA, int KGa, int kgoffA,
            unsigned short* __restrict__ dB, int KGb, int kgoffB)
{
    const int tid = blockIdx.x * 256 + threadIdx.x;   // B*H threads
    const int b = tid >> 10;
    const int u = tid & (HH - 1);

    float gi = bih[u]          + bhh[u];
    float gf = bih[HH + u]     + bhh[HH + u];
    float gg = bih[2 * HH + u] + bhh[2 * HH + u];
    float go = bih[3 * HH + u] + bhh[3 * HH + u];

#pragma unroll
    for (int s = 0; s < NSPLIT; s++) {
        const float* ps = P + (size_t)s * (BB * NG) + (size_t)b * NG;
        gi += ps[u];
        gf += ps[HH + u];
        gg += ps[2 * HH + u];
        go += ps[3 * HH + u];
    }

    const float si = 1.0f / (1.0f + expf(-gi));
    const float sf = 1.0f / (1.0f + expf(-gf));
    const float so = 1.0f / (1.0f + expf(-go));
    const float cn = sf * c[tid] + si * tanhf(gg);
    const float hn = so * tanhf(cn);
    c[tid] = cn;

    unsigned short hi, lo;
    split_bf16(hn, &hi, &lo);
    const int kg = u >> 3, j = u & 7;
    unsigned short* oa = dA + (((size_t)b * KGa + kgoffA + kg) << 4);
    oa[j]     = hi;
    oa[8 + j] = lo;
    unsigned short* ob = dB + (((size_t)b * KGb + kgoffB + kg) << 4);
    ob[j]     = hi;
    ob[8 + j] = lo;
}

// ---------------------------------------------------------------------------
// logits_frag_k: 64x32 logits tile, full K=1024, argmax-partial epilogue.
// Grid: 1000 blocks (4 blocks/CU -> 16 waves/CU for latency hiding).
// ---------------------------------------------------------------------------
__global__ __launch_bounds__(256)
void logits_frag_k(const unsigned short* __restrict__ A2,
                   const unsigned short* __restrict__ W2,
                   const float* __restrict__ bout,
                   float* __restrict__ pv, int* __restrict__ pi)
{
    __shared__ float rv[64][16];
    __shared__ int   ri[64][16];

    const int n0  = blockIdx.x * 32;
    const int tid = threadIdx.x;
    const int wv = tid >> 6, lane = tid & 63, l15 = lane & 15, q = lane >> 4;

    const unsigned short* pa  = A2 + (((size_t)(16 * wv + l15) * KGL + q) << 4);
    const unsigned short* pw0 = W2 + (((size_t)(n0 + l15)      * KGL + q) << 4);
    const unsigned short* pw1 = W2 + (((size_t)(n0 + 16 + l15) * KGL + q) << 4);

    f32x4 a0 = {0, 0, 0, 0}, a1 = {0, 0, 0, 0};
    kloop(pa, pw0, pw1, 32, a0, a1);

    // epilogue: +bias, argmax partials. col0 = n0+l15 < col1 = n0+16+l15.
#pragma unroll
    for (int reg = 0; reg < 4; reg++) {
        const int id0 = n0 + l15, id1 = n0 + 16 + l15;
        const float v0 = a0[reg] + bout[id0];
        const float v1 = a1[reg] + bout[id1];
        float best = v0; int bid = id0;
        if (v1 > best) { best = v1; bid = id1; }     // strict >: lower id wins tie
        rv[16 * wv + q * 4 + reg][l15] = best;
        ri[16 * wv + q * 4 + reg][l15] = bid;
    }
    __syncthreads();

    if (tid < 64) {
        float best = -INFINITY;
        int bid = 0x7fffffff;
        for (int k = 0; k < 16; k++) {               // ascending l15 = ascending id
            const float v = rv[tid][k];
            if (v > best) { best = v; bid = ri[tid][k]; }
        }
        pv[(size_t)tid * LBLK + blockIdx.x] = best;
        pi[(size_t)tid * LBLK + blockIdx.x] = bid;
    }
}

// ---------------------------------------------------------------------------
// final_k: reduce LBLK argmax partials per row -> token; gather embed row and
// emit it pre-split into the layer-0 A-fragment buffer (x-part).
// ---------------------------------------------------------------------------
__global__ __launch_bounds__(256)
void final_k(const float* __restrict__ pv, const int* __restrict__ pi,
             const float* __restrict__ embed, unsigned short* __restrict__ A2x,
             int* __restrict__ out, int t)
{
    __shared__ float sv[256];
    __shared__ int   si[256];
    const int b = blockIdx.x;
    const int tid = threadIdx.x;

    float best = -INFINITY;
    int bid = 0x7fffffff;
    for (int k = tid; k < LBLK; k += 256) {
        float v = pv[(size_t)b * LBLK + k];
        int id = pi[(size_t)b * LBLK + k];
        if (v > best || (v == best && id < bid)) { best = v; bid = id; }
    }
    sv[tid] = best; si[tid] = bid;
    __syncthreads();
    for (int s = 128; s > 0; s >>= 1) {
        if (tid < s) {
            float v = sv[tid + s]; int id = si[tid + s];
            if (v > sv[tid] || (v == sv[tid] && id < si[tid])) { sv[tid] = v; si[tid] = id; }
        }
        __syncthreads();
    }
    const int pred = si[0];
    if (tid == 0) out[(size_t)b * TT + t] = pred;

    for (int d = tid; d < DD; d += 256) {
        const float v = embed[(size_t)pred * DD + d];
        unsigned short hi, lo;
        split_bf16(v, &hi, &lo);
        unsigned short* o = A2x + (((size_t)b * KGC0 + (d >> 3)) << 4);
        o[(d & 7)]     = hi;
        o[8 + (d & 7)] = lo;
    }
}

// ---------------------------------------------------------------------------
extern "C" void kernel_launch(void* const* d_in, const int* in_sizes, int n_in,
                              void* d_out, int out_size, void* d_ws, size_t ws_size,
                              hipStream_t stream)
{
    const float* features = (const float*)d_in[0];
    const float* embed    = (const float*)d_in[1];
    const float* Wih0     = (const float*)d_in[2];
    const float* Whh0     = (const float*)d_in[3];
    const float* bih0     = (const float*)d_in[4];
    const float* bhh0     = (const float*)d_in[5];
    const float* Wih1     = (const float*)d_in[6];
    const float* Whh1     = (const float*)d_in[7];
    const float* bih1     = (const float*)d_in[8];
    const float* bhh1     = (const float*)d_in[9];
    const float* Wout     = (const float*)d_in[10];
    const float* bout     = (const float*)d_in[11];
    int* out = (int*)d_out;

    // workspace: ~9 MB fp32 + ~1 MB activation frags + ~190 MB weight frags
    float* ws   = (float*)d_ws;
    float* c0   = ws;                                    // B*H
    float* c1   = c0 + BB * HH;                          // B*H
    float* part = c1 + BB * HH;                          // NSPLIT*B*NG
    float* pv   = part + (size_t)NSPLIT * BB * NG;       // B*LBLK
    int*   pi   = (int*)(pv + (size_t)BB * LBLK);        // B*LBLK
    unsigned short* A2c0 = (unsigned short*)(pi + (size_t)BB * LBLK); // B*KGC0*16
    unsigned short* A2c1 = A2c0 + (size_t)BB * KGC0 * 16;             // B*KGC1*16
    unsigned short* A2l  = A2c1 + (size_t)BB * KGC1 * 16;             // B*KGL*16
    unsigned short* W2g0 = A2l  + (size_t)BB * KGL  * 16;             // 4096*KGC0*16
    unsigned short* W2g1 = W2g0 + (size_t)NG * KGC0 * 16;             // 4096*KGC1*16
    unsigned short* W2o  = W2g1 + (size_t)NG * KGC1 * 16;             // 32000*KGL*16

    // zero c-state and activation fragment buffers (h=0, c=0 at t=0)
    hipMemsetAsync(c0, 0, (size_t)2 * BB * HH * sizeof(float), stream);
    hipMemsetAsync(A2c0, 0,
                   (size_t)BB * (KGC0 + KGC1 + KGL) * 16 * sizeof(unsigned short),
                   stream);

    const dim3 blk(256);

    // one-time (per launch) weight/feature splits into fragment layout
    split_mat_k<<<dim3(NG * 64 / 256),      blk, 0, stream>>>(Wih0, W2g0, 6, KGC0, 0);
    split_mat_k<<<dim3(NG * 128 / 256),     blk, 0, stream>>>(Whh0, W2g0, 7, KGC0, 64);
    split_mat_k<<<dim3(NG * 128 / 256),     blk, 0, stream>>>(Wih1, W2g1, 7, KGC1, 0);
    split_mat_k<<<dim3(NG * 128 / 256),     blk, 0, stream>>>(Whh1, W2g1, 7, KGC1, 128);
    split_mat_k<<<dim3(VV * KGL / 256),     blk, 0, stream>>>(Wout, W2o, 7, KGL, 0);
    split_mat_k<<<dim3(BB * 64 / 256),      blk, 0, stream>>>(features, A2c0, 6, KGC0, 0);

    const dim3 ggate(NG / 32, NSPLIT);
    const dim3 gcell(BB * HH / 256);
    const dim3 glog(LBLK);
    const dim3 gfin(BB);

    for (int t = 0; t < TT; t++) {
        // layer 0: gates over concat(x, h0), K=1536 -> 6 windows/slice
        gates_mfma_k<<<ggate, blk, 0, stream>>>(A2c0, W2g0, KGC0, 6, part);
        cell_k<<<gcell, blk, 0, stream>>>(part, bih0, bhh0, c0,
                                          A2c0, KGC0, 64,    // h0 for next-step layer0
                                          A2c1, KGC1, 0);    // h0 for this-step layer1
        // layer 1: gates over concat(h0, h1), K=2048 -> 8 windows/slice
        gates_mfma_k<<<ggate, blk, 0, stream>>>(A2c1, W2g1, KGC1, 8, part);
        cell_k<<<gcell, blk, 0, stream>>>(part, bih1, bhh1, c1,
                                          A2c1, KGC1, 128,   // h1 for next-step layer1
                                          A2l,  KGL,  0);    // h1 for logits
        // output projection + argmax partials
        logits_frag_k<<<glog, blk, 0, stream>>>(A2l, W2o, bout, pv, pi);
        // argmax reduce + token write + embedding gather (pre-split)
        final_k<<<gfin, blk, 0, stream>>>(pv, pi, embed, A2c0, out, t);
    }
}

// Round 5
// 3215.611 us; speedup vs baseline: 1.5101x; 1.5101x over previous
//
#include <hip/hip_runtime.h>
#include <math.h>
#include <stdint.h>

// SentenceDecoder: B=64, D=512, H=1024, V=32000, L=2, T=32. NG = 4H = 4096.
// All GEMMs: split-bf16 MFMA (x = hi + lo bf16; 3 MFMA per hi/lo pair:
// ah*bl + al*bh + ah*bh, fp32 acc; rel err ~2^-17 — argmax-safe).
// Fragment layout: [(row*KG + kg)*16 + {0..7 hi, 8..15 lo}] ushorts, kg = k/8.
// GEMM kernels use m97-style LDS staging: global_load_lds(width=16) async
// DMA -> barrier -> ds_read_b128 fragments -> MFMA. (r3/r4 showed the
// compiler will NOT pipeline register-resident global loads across MFMAs.)
#define BB 64
#define DD 512
#define HH 1024
#define VV 32000
#define NG 4096
#define TT 32
#define NSPLIT 8            // K-slices for gate GEMMs
#define LBLK 1000           // V / 32 logits tiles
#define KGC0 192            // kg/row, layer-0 concat K=1536 (x512|h1024)
#define KGC1 256            // layer-1 concat K=2048 (h0|h1)
#define KGL  128            // logits K=1024

typedef __bf16 bf16x8 __attribute__((ext_vector_type(8)));
typedef float  f32x4  __attribute__((ext_vector_type(4)));

__device__ __forceinline__ void split_bf16(float x, unsigned short* hi, unsigned short* lo)
{
    unsigned u = __float_as_uint(x);
    unsigned r = (u + 0x7fffu + ((u >> 16) & 1u)) & 0xffff0000u;
    *hi = (unsigned short)(r >> 16);
    float rem = x - __uint_as_float(r);
    unsigned u2 = __float_as_uint(rem);
    unsigned r2 = u2 + 0x7fffu + ((u2 >> 16) & 1u);
    *lo = (unsigned short)(r2 >> 16);
}

__device__ __forceinline__ unsigned pack2(unsigned short a, unsigned short b)
{
    return (unsigned)a | ((unsigned)b << 16);
}

// async global->LDS, 16 B per lane (global addr per-lane; LDS dest must be
// wave-contiguous: base + lane*16)
__device__ __forceinline__ void gl2lds16(const void* g, void* l)
{
    __builtin_amdgcn_global_load_lds(
        (const __attribute__((address_space(1))) unsigned int*)(uintptr_t)g,
        (__attribute__((address_space(3))) unsigned int*)(uintptr_t)l,
        16, 0, 0);
}

// ---------------------------------------------------------------------------
// split_mat_k: fp32 [R][Ksrc] -> split fragment layout at kg offset.
// One thread per (row, kg): Ksrc = 8<<kshift.
// ---------------------------------------------------------------------------
__global__ __launch_bounds__(256)
void split_mat_k(const float* __restrict__ src, unsigned short* __restrict__ dst,
                 int kshift, int KGdst, int kgoff)
{
    const size_t t = (size_t)blockIdx.x * 256 + threadIdx.x;
    const int row = (int)(t >> kshift);
    const int kg  = (int)(t & ((1u << kshift) - 1));
    const float* wp = src + (t << 3);
    const float4 w0 = *(const float4*)wp;
    const float4 w1 = *(const float4*)(wp + 4);
    const float v[8] = {w0.x, w0.y, w0.z, w0.w, w1.x, w1.y, w1.z, w1.w};
    unsigned short hs[8], ls[8];
#pragma unroll
    for (int i = 0; i < 8; i++) split_bf16(v[i], &hs[i], &ls[i]);
    uint4 uh, ul;
    uh.x = pack2(hs[0], hs[1]); uh.y = pack2(hs[2], hs[3]);
    uh.z = pack2(hs[4], hs[5]); uh.w = pack2(hs[6], hs[7]);
    ul.x = pack2(ls[0], ls[1]); ul.y = pack2(ls[2], ls[3]);
    ul.z = pack2(ls[4], ls[5]); ul.w = pack2(ls[6], ls[7]);
    unsigned short* o = dst + (((size_t)row * KGdst + kgoff + kg) << 4);
    *(uint4*)o       = uh;
    *(uint4*)(o + 8) = ul;
}

// ---------------------------------------------------------------------------
// Staged K-loop core: M=64 (batch) x N=32 tile, BK=64 (8 kg) per chunk.
// Alds: 64 rows x 128 ushorts (16 KB). Wlds: 32 rows x 128 ushorts (8 KB).
// Per chunk: 6 global_load_lds issues/wave (async), barrier, 12 ds_read_b128
// + 12 MFMA per wave (2 k-windows x 2 col-tiles x 3).
// ---------------------------------------------------------------------------
__device__ __forceinline__ void kloop_lds(const unsigned short* __restrict__ A2, int KGA,
                                          const unsigned short* __restrict__ W2, int KGW,
                                          int n0, int kgbase, int nchunks,
                                          unsigned short* Alds, unsigned short* Wlds,
                                          int wv, int lane, int l15, int q,
                                          f32x4& a0, f32x4& a1)
{
    for (int ch = 0; ch < nchunks; ++ch) {
        const int kg0 = kgbase + ch * 8;
        __syncthreads();
        // stage A tile: 1024 16B-chunks, 4 issues/wave
#pragma unroll
        for (int i = 0; i < 4; ++i) {
            const int c = 256 * wv + 64 * i + lane;
            const int row = c >> 4, sub = c & 15;
            gl2lds16(A2 + (((size_t)row * KGA + kg0) << 4) + sub * 8, Alds + c * 8);
        }
        // stage W tile: 512 16B-chunks, 2 issues/wave
#pragma unroll
        for (int i = 0; i < 2; ++i) {
            const int c = 128 * wv + 64 * i + lane;
            const int row = c >> 4, sub = c & 15;
            gl2lds16(W2 + (((size_t)(n0 + row) * KGW + kg0) << 4) + sub * 8, Wlds + c * 8);
        }
        __syncthreads();
#pragma unroll
        for (int w = 0; w < 2; ++w) {
            const int kk = (4 * w + q) * 16;
            bf16x8 ah  = *(const bf16x8*)&Alds[(16 * wv + l15) * 128 + kk];
            bf16x8 al  = *(const bf16x8*)&Alds[(16 * wv + l15) * 128 + kk + 8];
            bf16x8 b0h = *(const bf16x8*)&Wlds[l15 * 128 + kk];
            bf16x8 b0l = *(const bf16x8*)&Wlds[l15 * 128 + kk + 8];
            bf16x8 b1h = *(const bf16x8*)&Wlds[(16 + l15) * 128 + kk];
            bf16x8 b1l = *(const bf16x8*)&Wlds[(16 + l15) * 128 + kk + 8];
            a0 = __builtin_amdgcn_mfma_f32_16x16x32_bf16(ah, b0l, a0, 0, 0, 0);
            a0 = __builtin_amdgcn_mfma_f32_16x16x32_bf16(al, b0h, a0, 0, 0, 0);
            a0 = __builtin_amdgcn_mfma_f32_16x16x32_bf16(ah, b0h, a0, 0, 0, 0);
            a1 = __builtin_amdgcn_mfma_f32_16x16x32_bf16(ah, b1l, a1, 0, 0, 0);
            a1 = __builtin_amdgcn_mfma_f32_16x16x32_bf16(al, b1h, a1, 0, 0, 0);
            a1 = __builtin_amdgcn_mfma_f32_16x16x32_bf16(ah, b1h, a1, 0, 0, 0);
        }
    }
}

// ---------------------------------------------------------------------------
// gates_lds_k: partial gate GEMM, 64x32 tile, K-slice = blockIdx.y.
// Grid (128, NSPLIT). P[slice][b][j] = sum_{k in slice} A[b][k]*W[j][k].
// ---------------------------------------------------------------------------
__global__ __launch_bounds__(256)
void gates_lds_k(const unsigned short* __restrict__ A2,
                 const unsigned short* __restrict__ W2,
                 int KGk, int nchunks, float* __restrict__ P)
{
    __shared__ __align__(16) unsigned short smem[(64 + 32) * 128];  // 24 KB
    unsigned short* Alds = smem;
    unsigned short* Wlds = smem + 64 * 128;

    const int n0  = blockIdx.x * 32;
    const int tid = threadIdx.x;
    const int wv = tid >> 6, lane = tid & 63, l15 = lane & 15, q = lane >> 4;
    const int kgbase = blockIdx.y * (KGk / NSPLIT);

    f32x4 a0 = {0, 0, 0, 0}, a1 = {0, 0, 0, 0};
    kloop_lds(A2, KGk, W2, KGk, n0, kgbase, nchunks, Alds, Wlds,
              wv, lane, l15, q, a0, a1);

    float* __restrict__ Pout = P + (size_t)blockIdx.y * (BB * NG);
    // C/D: col = lane&15 (n), row = q*4 + reg (m)
#pragma unroll
    for (int reg = 0; reg < 4; reg++) {
        const int b = 16 * wv + q * 4 + reg;
        Pout[(size_t)b * NG + n0 + l15]      = a0[reg];
        Pout[(size_t)b * NG + n0 + 16 + l15] = a1[reg];
    }
}

// ---------------------------------------------------------------------------
// logits_lds_k: 64x32 logits tile, full K=1024, argmax-partial epilogue.
// Grid: 1000 blocks.
// ---------------------------------------------------------------------------
__global__ __launch_bounds__(256)
void logits_lds_k(const unsigned short* __restrict__ A2,
                  const unsigned short* __restrict__ W2,
                  const float* __restrict__ bout,
                  float* __restrict__ pv, int* __restrict__ pi)
{
    __shared__ __align__(16) unsigned short smem[(64 + 32) * 128];  // 24 KB
    unsigned short* Alds = smem;
    unsigned short* Wlds = smem + 64 * 128;
    // epilogue scratch aliases the A tile (8 KB <= 16 KB), barrier-protected
    float* rv = (float*)smem;               // [64][16]
    int*   ri = (int*)(rv + 64 * 16);       // [64][16]

    const int n0  = blockIdx.x * 32;
    const int tid = threadIdx.x;
    const int wv = tid >> 6, lane = tid & 63, l15 = lane & 15, q = lane >> 4;

    f32x4 a0 = {0, 0, 0, 0}, a1 = {0, 0, 0, 0};
    kloop_lds(A2, KGL, W2, KGL, n0, 0, 16, Alds, Wlds,
              wv, lane, l15, q, a0, a1);

    __syncthreads();   // protect smem reuse (all ds_reads of the K-loop done)

    // +bias, per-reg argmax over this block's 32 cols. id0 < id1 always.
#pragma unroll
    for (int reg = 0; reg < 4; reg++) {
        const int id0 = n0 + l15, id1 = n0 + 16 + l15;
        const float v0 = a0[reg] + bout[id0];
        const float v1 = a1[reg] + bout[id1];
        float best = v0; int bid = id0;
        if (v1 > best) { best = v1; bid = id1; }   // strict >: lower id wins tie
        rv[(16 * wv + q * 4 + reg) * 16 + l15] = best;
        ri[(16 * wv + q * 4 + reg) * 16 + l15] = bid;
    }
    __syncthreads();

    if (tid < 64) {
        float best = -INFINITY;
        int bid = 0x7fffffff;
        for (int k = 0; k < 16; k++) {             // ascending l15 = ascending id
            const float v = rv[tid * 16 + k];
            if (v > best) { best = v; bid = ri[tid * 16 + k]; }
        }
        pv[(size_t)tid * LBLK + blockIdx.x] = best;
        pi[(size_t)tid * LBLK + blockIdx.x] = bid;
    }
}

// ---------------------------------------------------------------------------
// cell_k: sum NSPLIT partial slices + biases -> gates; LSTM cell; emit split
// h into two fragment-layout destinations.
// ---------------------------------------------------------------------------
__global__ __launch_bounds__(256)
void cell_k(const float* __restrict__ P, const float* __restrict__ bih,
            const float* __restrict__ bhh, float* __restrict__ c,
            unsigned short* __restrict__ dA, int KGa, int kgoffA,
            unsigned short* __restrict__ dB, int KGb, int kgoffB)
{
    const int tid = blockIdx.x * 256 + threadIdx.x;   // B*H threads
    const int b = tid >> 10;
    const int u = tid & (HH - 1);

    float gi = bih[u]          + bhh[u];
    float gf = bih[HH + u]     + bhh[HH + u];
    float gg = bih[2 * HH + u] + bhh[2 * HH + u];
    float go = bih[3 * HH + u] + bhh[3 * HH + u];

#pragma unroll
    for (int s = 0; s < NSPLIT; s++) {
        const float* ps = P + (size_t)s * (BB * NG) + (size_t)b * NG;
        gi += ps[u];
        gf += ps[HH + u];
        gg += ps[2 * HH + u];
        go += ps[3 * HH + u];
    }

    const float si = 1.0f / (1.0f + expf(-gi));
    const float sf = 1.0f / (1.0f + expf(-gf));
    const float so = 1.0f / (1.0f + expf(-go));
    const float cn = sf * c[tid] + si * tanhf(gg);
    const float hn = so * tanhf(cn);
    c[tid] = cn;

    unsigned short hi, lo;
    split_bf16(hn, &hi, &lo);
    const int kg = u >> 3, j = u & 7;
    unsigned short* oa = dA + (((size_t)b * KGa + kgoffA + kg) << 4);
    oa[j]     = hi;
    oa[8 + j] = lo;
    unsigned short* ob = dB + (((size_t)b * KGb + kgoffB + kg) << 4);
    ob[j]     = hi;
    ob[8 + j] = lo;
}

// ---------------------------------------------------------------------------
// final_k: reduce LBLK argmax partials -> token; gather embed row pre-split
// into the layer-0 A-fragment buffer.
// ---------------------------------------------------------------------------
__global__ __launch_bounds__(256)
void final_k(const float* __restrict__ pv, const int* __restrict__ pi,
             const float* __restrict__ embed, unsigned short* __restrict__ A2x,
             int* __restrict__ out, int t)
{
    __shared__ float sv[256];
    __shared__ int   si[256];
    const int b = blockIdx.x;
    const int tid = threadIdx.x;

    float best = -INFINITY;
    int bid = 0x7fffffff;
    for (int k = tid; k < LBLK; k += 256) {
        float v = pv[(size_t)b * LBLK + k];
        int id = pi[(size_t)b * LBLK + k];
        if (v > best || (v == best && id < bid)) { best = v; bid = id; }
    }
    sv[tid] = best; si[tid] = bid;
    __syncthreads();
    for (int s = 128; s > 0; s >>= 1) {
        if (tid < s) {
            float v = sv[tid + s]; int id = si[tid + s];
            if (v > sv[tid] || (v == sv[tid] && id < si[tid])) { sv[tid] = v; si[tid] = id; }
        }
        __syncthreads();
    }
    const int pred = si[0];
    if (tid == 0) out[(size_t)b * TT + t] = pred;

    for (int d = tid; d < DD; d += 256) {
        const float v = embed[(size_t)pred * DD + d];
        unsigned short hi, lo;
        split_bf16(v, &hi, &lo);
        unsigned short* o = A2x + (((size_t)b * KGC0 + (d >> 3)) << 4);
        o[(d & 7)]     = hi;
        o[8 + (d & 7)] = lo;
    }
}

// ---------------------------------------------------------------------------
extern "C" void kernel_launch(void* const* d_in, const int* in_sizes, int n_in,
                              void* d_out, int out_size, void* d_ws, size_t ws_size,
                              hipStream_t stream)
{
    const float* features = (const float*)d_in[0];
    const float* embed    = (const float*)d_in[1];
    const float* Wih0     = (const float*)d_in[2];
    const float* Whh0     = (const float*)d_in[3];
    const float* bih0     = (const float*)d_in[4];
    const float* bhh0     = (const float*)d_in[5];
    const float* Wih1     = (const float*)d_in[6];
    const float* Whh1     = (const float*)d_in[7];
    const float* bih1     = (const float*)d_in[8];
    const float* bhh1     = (const float*)d_in[9];
    const float* Wout     = (const float*)d_in[10];
    const float* bout     = (const float*)d_in[11];
    int* out = (int*)d_out;

    float* ws   = (float*)d_ws;
    float* c0   = ws;                                    // B*H
    float* c1   = c0 + BB * HH;                          // B*H
    float* part = c1 + BB * HH;                          // NSPLIT*B*NG
    float* pv   = part + (size_t)NSPLIT * BB * NG;       // B*LBLK
    int*   pi   = (int*)(pv + (size_t)BB * LBLK);        // B*LBLK
    unsigned short* A2c0 = (unsigned short*)(pi + (size_t)BB * LBLK); // B*KGC0*16
    unsigned short* A2c1 = A2c0 + (size_t)BB * KGC0 * 16;             // B*KGC1*16
    unsigned short* A2l  = A2c1 + (size_t)BB * KGC1 * 16;             // B*KGL*16
    unsigned short* W2g0 = A2l  + (size_t)BB * KGL  * 16;             // NG*KGC0*16
    unsigned short* W2g1 = W2g0 + (size_t)NG * KGC0 * 16;             // NG*KGC1*16
    unsigned short* W2o  = W2g1 + (size_t)NG * KGC1 * 16;             // VV*KGL*16

    hipMemsetAsync(c0, 0, (size_t)2 * BB * HH * sizeof(float), stream);
    hipMemsetAsync(A2c0, 0,
                   (size_t)BB * (KGC0 + KGC1 + KGL) * 16 * sizeof(unsigned short),
                   stream);

    const dim3 blk(256);

    // per-launch weight/feature splits into fragment layout
    split_mat_k<<<dim3(NG * 64 / 256),  blk, 0, stream>>>(Wih0, W2g0, 6, KGC0, 0);
    split_mat_k<<<dim3(NG * 128 / 256), blk, 0, stream>>>(Whh0, W2g0, 7, KGC0, 64);
    split_mat_k<<<dim3(NG * 128 / 256), blk, 0, stream>>>(Wih1, W2g1, 7, KGC1, 0);
    split_mat_k<<<dim3(NG * 128 / 256), blk, 0, stream>>>(Whh1, W2g1, 7, KGC1, 128);
    split_mat_k<<<dim3(VV * KGL / 256), blk, 0, stream>>>(Wout, W2o, 7, KGL, 0);
    split_mat_k<<<dim3(BB * 64 / 256),  blk, 0, stream>>>(features, A2c0, 6, KGC0, 0);

    const dim3 ggate(NG / 32, NSPLIT);
    const dim3 gcell(BB * HH / 256);
    const dim3 glog(LBLK);
    const dim3 gfin(BB);

    for (int t = 0; t < TT; t++) {
        // layer 0: K=1536 -> 24 kg/slice -> 3 chunks
        gates_lds_k<<<ggate, blk, 0, stream>>>(A2c0, W2g0, KGC0, 3, part);
        cell_k<<<gcell, blk, 0, stream>>>(part, bih0, bhh0, c0,
                                          A2c0, KGC0, 64,    // h0 -> next-step layer0
                                          A2c1, KGC1, 0);    // h0 -> this-step layer1
        // layer 1: K=2048 -> 32 kg/slice -> 4 chunks
        gates_lds_k<<<ggate, blk, 0, stream>>>(A2c1, W2g1, KGC1, 4, part);
        cell_k<<<gcell, blk, 0, stream>>>(part, bih1, bhh1, c1,
                                          A2c1, KGC1, 128,   // h1 -> next-step layer1
                                          A2l,  KGL,  0);    // h1 -> logits
        // output projection + argmax partials
        logits_lds_k<<<glog, blk, 0, stream>>>(A2l, W2o, bout, pv, pi);
        // argmax reduce + token write + embedding gather (pre-split)
        final_k<<<gfin, blk, 0, stream>>>(pv, pi, embed, A2c0, out, t);
    }
}